// Round 2
// baseline (1337.677 us; speedup 1.0000x reference)
//
#include <hip/hip_runtime.h>
#include <stdint.h>

#define D 64
constexpr float NEG_SLOPE = 0.2f;

// order-preserving float->uint encoding for atomicMax on floats
__device__ __forceinline__ unsigned enc_f(float x){
  unsigned u = __float_as_uint(x);
  return (u & 0x80000000u) ? ~u : (u | 0x80000000u);
}
__device__ __forceinline__ float dec_f(unsigned u){
  return (u & 0x80000000u) ? __uint_as_float(u & 0x7fffffffu) : __uint_as_float(~u);
}

// ce[l] = sum_d We_l[d] * ae_l[d]  (the (he*a_edge).sum(-1) collapse)
__global__ void k_ce(const float* __restrict__ We1, const float* __restrict__ ae1,
                     const float* __restrict__ We2, const float* __restrict__ ae2,
                     float* __restrict__ ce){
  int lane = threadIdx.x;
  float p1 = We1[lane] * ae1[lane];
  float p2 = We2[lane] * ae2[lane];
  #pragma unroll
  for (int off = 32; off; off >>= 1){ p1 += __shfl_xor(p1, off); p2 += __shfl_xor(p2, off); }
  if (lane == 0){ ce[0] = p1; ce[1] = p2; }
}

// h = X @ W (wave-per-row, W in LDS), fused asrc[n]=h.as, adst[n]=h.ad
__global__ __launch_bounds__(256) void k_gemm_dots(
    const float* __restrict__ X, const float* __restrict__ W,
    const float* __restrict__ a_s, const float* __restrict__ a_d,
    float* __restrict__ H, float* __restrict__ asrc, float* __restrict__ adst, int n)
{
  __shared__ float sW[D * D];
  {
    const float4* Wv = (const float4*)W;
    float4* sWv = (float4*)sW;
    #pragma unroll
    for (int t = threadIdx.x; t < D * D / 4; t += 256) sWv[t] = Wv[t];
  }
  int lane = threadIdx.x & 63;
  int wid  = threadIdx.x >> 6;
  float asv = a_s[lane], adv = a_d[lane];
  __syncthreads();
  int r = blockIdx.x * 4 + wid;
  if (r >= n) return;
  float xv = X[(size_t)r * D + lane];
  float acc = 0.f;
  #pragma unroll
  for (int k = 0; k < D; ++k){
    float xk = __shfl(xv, k);                 // compile-time k -> readlane broadcast
    acc = fmaf(xk, sW[k * D + lane], acc);    // 2-way LDS aliasing = free
  }
  H[(size_t)r * D + lane] = acc;
  float ps = acc * asv, pd = acc * adv;
  #pragma unroll
  for (int off = 32; off; off >>= 1){ ps += __shfl_xor(ps, off); pd += __shfl_xor(pd, off); }
  if (lane == 0){ asrc[r] = ps; adst[r] = pd; }
}

// agg init to bias (so aggregation needs no epilogue pass); m_enc/denom zeroed
__global__ void k_init(float* __restrict__ agg, const float* __restrict__ bias,
                       unsigned* __restrict__ m_enc, float* __restrict__ denom, int n){
  int idx = blockIdx.x * blockDim.x + threadIdx.x;
  if (idx < n * D) agg[idx] = bias[idx & (D - 1)];
  if (idx < n){ m_enc[idx] = 0u; denom[idx] = 0.f; }
}

// per-edge: alpha = leaky_relu(asrc[s]+adst[d]+ea*ce); segment-max via atomicMax
__global__ void k_edge_alpha(const int* __restrict__ src, const int* __restrict__ dst,
    const float* __restrict__ ea, const float* __restrict__ asrc, const float* __restrict__ adst,
    const float* __restrict__ ce, int ce_idx, float* __restrict__ alpha,
    unsigned* __restrict__ m_enc, int e)
{
  int i = blockIdx.x * blockDim.x + threadIdx.x;
  if (i >= e) return;
  int s = src[i], d2 = dst[i];
  float a = asrc[s] + adst[d2] + ea[i] * ce[ce_idx];
  a = a > 0.f ? a : NEG_SLOPE * a;
  alpha[i] = a;
  atomicMax(&m_enc[d2], enc_f(a));
}

// per-edge: e = exp(alpha - m[dst]) (overwrites alpha buf); denom segment-sum
__global__ void k_edge_exp(const int* __restrict__ dst, float* __restrict__ alpha,
    const unsigned* __restrict__ m_enc, float* __restrict__ denom, int e)
{
  int i = blockIdx.x * blockDim.x + threadIdx.x;
  if (i >= e) return;
  int d2 = dst[i];
  float ev = __expf(alpha[i] - dec_f(m_enc[d2]));
  alpha[i] = ev;
  atomicAdd(&denom[d2], ev);
}

// wave-per-edge: out[dst] += h[src] * e/(denom[dst]+eps); lane = feature dim
__global__ __launch_bounds__(256) void k_edge_aggr(
    const int* __restrict__ src, const int* __restrict__ dst,
    const float* __restrict__ earr, const float* __restrict__ denom,
    const float* __restrict__ H, float* __restrict__ out, int e)
{
  int lane = threadIdx.x & 63;
  int wid = (blockIdx.x * blockDim.x + threadIdx.x) >> 6;
  int nw  = (gridDim.x * blockDim.x) >> 6;
  for (int i = wid; i < e; i += nw){
    int s = src[i], d2 = dst[i];
    float w = earr[i] / (denom[d2] + 1e-16f);
    float hv = H[(size_t)s * D + lane];
    atomicAdd(&out[(size_t)d2 * D + lane], hv * w);
  }
}

__global__ void k_relu(float* __restrict__ x, int total){
  int idx = blockIdx.x * blockDim.x + threadIdx.x;
  if (idx < total) x[idx] = fmaxf(x[idx], 0.f);
}

extern "C" void kernel_launch(void* const* d_in, const int* in_sizes, int n_in,
                              void* d_out, int out_size, void* d_ws, size_t ws_size,
                              hipStream_t stream)
{
  const float* x    = (const float*)d_in[0];
  const int*   ei   = (const int*)d_in[1];    // harness passes integer inputs as int32
  const float* ea   = (const float*)d_in[2];
  const float* W1   = (const float*)d_in[3];
  const float* We1  = (const float*)d_in[4];
  const float* as1  = (const float*)d_in[5];
  const float* ad1  = (const float*)d_in[6];
  const float* ae1  = (const float*)d_in[7];
  const float* b1   = (const float*)d_in[8];
  const float* W2   = (const float*)d_in[9];
  const float* We2  = (const float*)d_in[10];
  const float* as2  = (const float*)d_in[11];
  const float* ad2  = (const float*)d_in[12];
  const float* ae2  = (const float*)d_in[13];
  const float* b2   = (const float*)d_in[14];
  float* out = (float*)d_out;

  int n = in_sizes[0] / D;     // 100000
  int e = in_sizes[1] / 2;     // 1600000
  const int* srcp = ei;
  const int* dstp = ei + e;

  char* p = (char*)d_ws;
  float*    buf_h  = (float*)p;    p += (size_t)n * D * 4;   // transformed feats
  float*    buf_x2 = (float*)p;    p += (size_t)n * D * 4;   // layer-1 out / layer-2 in
  float*    asrc   = (float*)p;    p += (size_t)n * 4;
  float*    adst   = (float*)p;    p += (size_t)n * 4;
  float*    denom  = (float*)p;    p += (size_t)n * 4;
  unsigned* m_enc  = (unsigned*)p; p += (size_t)n * 4;
  float*    alpha  = (float*)p;    p += (size_t)e * 4;       // alpha, then e, in place
  float*    ce     = (float*)p;    p += 16;

  int gE    = (e + 255) / 256;
  int gN64  = (n * D + 255) / 256;
  int gR    = (n + 3) / 4;
  int gAgg  = 4096;   // 16384 waves, ~98 edges each

  k_ce<<<1, 64, 0, stream>>>(We1, ae1, We2, ae2, ce);

  // ---- layer 1 ----
  k_gemm_dots<<<gR, 256, 0, stream>>>(x, W1, as1, ad1, buf_h, asrc, adst, n);
  k_init<<<gN64, 256, 0, stream>>>(buf_x2, b1, m_enc, denom, n);
  k_edge_alpha<<<gE, 256, 0, stream>>>(srcp, dstp, ea, asrc, adst, ce, 0, alpha, m_enc, e);
  k_edge_exp<<<gE, 256, 0, stream>>>(dstp, alpha, m_enc, denom, e);
  k_edge_aggr<<<gAgg, 256, 0, stream>>>(srcp, dstp, alpha, denom, buf_h, buf_x2, e);
  k_relu<<<gN64, 256, 0, stream>>>(buf_x2, n * D);

  // ---- layer 2 ----
  k_gemm_dots<<<gR, 256, 0, stream>>>(buf_x2, W2, as2, ad2, buf_h, asrc, adst, n);
  k_init<<<gN64, 256, 0, stream>>>(out, b2, m_enc, denom, n);
  k_edge_alpha<<<gE, 256, 0, stream>>>(srcp, dstp, ea, asrc, adst, ce, 1, alpha, m_enc, e);
  k_edge_exp<<<gE, 256, 0, stream>>>(dstp, alpha, m_enc, denom, e);
  k_edge_aggr<<<gAgg, 256, 0, stream>>>(srcp, dstp, alpha, denom, buf_h, out, e);
}

// Round 3
// 728.485 us; speedup vs baseline: 1.8362x; 1.8362x over previous
//
#include <hip/hip_runtime.h>
#include <stdint.h>

#define D 64
constexpr float NEG_SLOPE = 0.2f;

// ce[l] = sum_d We_l[d] * ae_l[d]
__global__ void k_ce(const float* __restrict__ We1, const float* __restrict__ ae1,
                     const float* __restrict__ We2, const float* __restrict__ ae2,
                     float* __restrict__ ce){
  int lane = threadIdx.x;
  float p1 = We1[lane] * ae1[lane];
  float p2 = We2[lane] * ae2[lane];
  #pragma unroll
  for (int off = 32; off; off >>= 1){ p1 += __shfl_xor(p1, off); p2 += __shfl_xor(p2, off); }
  if (lane == 0){ ce[0] = p1; ce[1] = p2; }
}

// h = X @ W (wave-per-row, W in LDS), fused asrc[n]=h.as, adst[n]=h.ad
__global__ __launch_bounds__(256) void k_gemm_dots(
    const float* __restrict__ X, const float* __restrict__ W,
    const float* __restrict__ a_s, const float* __restrict__ a_d,
    float* __restrict__ H, float* __restrict__ asrc, float* __restrict__ adst, int n)
{
  __shared__ float sW[D * D];
  {
    const float4* Wv = (const float4*)W;
    float4* sWv = (float4*)sW;
    #pragma unroll
    for (int t = threadIdx.x; t < D * D / 4; t += 256) sWv[t] = Wv[t];
  }
  int lane = threadIdx.x & 63;
  int wid  = threadIdx.x >> 6;
  float asv = a_s[lane], adv = a_d[lane];
  __syncthreads();
  int r = blockIdx.x * 4 + wid;
  if (r >= n) return;
  float xv = X[(size_t)r * D + lane];
  float acc = 0.f;
  #pragma unroll
  for (int k = 0; k < D; ++k){
    float xk = __shfl(xv, k);
    acc = fmaf(xk, sW[k * D + lane], acc);
  }
  H[(size_t)r * D + lane] = acc;
  float ps = acc * asv, pd = acc * adv;
  #pragma unroll
  for (int off = 32; off; off >>= 1){ ps += __shfl_xor(ps, off); pd += __shfl_xor(pd, off); }
  if (lane == 0){ asrc[r] = ps; adst[r] = pd; }
}

// ---------------- CSR build (once per call) ----------------

__global__ void k_zero(int* __restrict__ deg, int n){
  int i = blockIdx.x * blockDim.x + threadIdx.x;
  if (i < n) deg[i] = 0;
}

__global__ void k_hist(const int* __restrict__ dst, int* __restrict__ deg, int e){
  int i = blockIdx.x * blockDim.x + threadIdx.x;
  if (i < e) atomicAdd(&deg[dst[i]], 1);
}

// block-level inclusive scan (256/block) + block sums
__global__ __launch_bounds__(256) void k_scan1(const int* __restrict__ deg,
    int* __restrict__ incl, int* __restrict__ bsum, int n){
  __shared__ int s[256];
  int tid = threadIdx.x;
  int idx = blockIdx.x * 256 + tid;
  int v = (idx < n) ? deg[idx] : 0;
  s[tid] = v; __syncthreads();
  #pragma unroll
  for (int off = 1; off < 256; off <<= 1){
    int t = (tid >= off) ? s[tid - off] : 0;
    __syncthreads();
    s[tid] += t;
    __syncthreads();
  }
  if (idx < n) incl[idx] = s[tid];
  if (tid == 255) bsum[blockIdx.x] = s[255];
}

// single-wave exclusive scan of block sums (nb <= 512)
__global__ void k_scan2(int* __restrict__ bsum, int nb){
  int lane = threadIdx.x;                // 64 threads
  int per = (nb + 63) / 64;              // <= 8
  int base = lane * per;
  int local[8];
  int s = 0;
  #pragma unroll
  for (int k = 0; k < 8; ++k){
    int idx = base + k;
    int v = (k < per && idx < nb) ? bsum[idx] : 0;
    local[k] = v; s += v;
  }
  int inc = s;
  #pragma unroll
  for (int off = 1; off < 64; off <<= 1){
    int t = __shfl_up(inc, off);
    if (lane >= off) inc += t;
  }
  int run = inc - s;                     // exclusive prefix for this lane
  #pragma unroll
  for (int k = 0; k < 8; ++k){
    int idx = base + k;
    if (k < per && idx < nb){ int v = local[k]; bsum[idx] = run; run += v; }
  }
}

// rowptr[i+1] = incl[i]+bsum_excl[blk]; cursor[i] = start offset; rowptr[0]=0
__global__ void k_scan3(const int* __restrict__ deg, const int* __restrict__ incl,
    const int* __restrict__ bsum, int* __restrict__ rowptr, int* __restrict__ cursor, int n){
  int idx = blockIdx.x * 256 + threadIdx.x;
  if (idx >= n) return;
  int inc = incl[idx] + bsum[blockIdx.x];
  rowptr[idx + 1] = inc;
  cursor[idx] = inc - deg[idx];
  if (idx == 0) rowptr[0] = 0;
}

__global__ void k_scatter(const int* __restrict__ src, const int* __restrict__ dst,
    const float* __restrict__ ea, int* __restrict__ cursor,
    int* __restrict__ src_sorted, float* __restrict__ ea_sorted, int e){
  int i = blockIdx.x * blockDim.x + threadIdx.x;
  if (i >= e) return;
  int d = dst[i];
  int pos = atomicAdd(&cursor[d], 1);
  src_sorted[pos] = src[i];
  ea_sorted[pos] = ea[i];
}

// ---------------- per-layer fused passes ----------------

// 16-lane subgroup per node: alpha, segment max, exp, denom — no atomics
__global__ __launch_bounds__(256) void k_node_softmax(
    const int* __restrict__ rowptr, const int* __restrict__ src_sorted,
    const float* __restrict__ ea_sorted, const float* __restrict__ asrc,
    const float* __restrict__ adst, const float* __restrict__ ce, int ce_idx,
    float* __restrict__ esort, float* __restrict__ denom, int n)
{
  int v  = (blockIdx.x * 256 + threadIdx.x) >> 4;   // node
  int ls = threadIdx.x & 15;
  if (v >= n) return;
  int start = rowptr[v], end = rowptr[v + 1];
  if (start == end){ if (ls == 0) denom[v] = 1.f; return; }
  float adv = adst[v];
  float cev = ce[ce_idx];
  float m = -1e30f;
  for (int j = start + ls; j < end; j += 16){
    float a = asrc[src_sorted[j]] + adv + ea_sorted[j] * cev;
    a = a > 0.f ? a : NEG_SLOPE * a;
    esort[j] = a;
    m = fmaxf(m, a);
  }
  #pragma unroll
  for (int off = 8; off; off >>= 1) m = fmaxf(m, __shfl_xor(m, off, 16));
  float ss = 0.f;
  for (int j = start + ls; j < end; j += 16){
    float ev = __expf(esort[j] - m);
    esort[j] = ev;
    ss += ev;
  }
  #pragma unroll
  for (int off = 8; off; off >>= 1) ss += __shfl_xor(ss, off, 16);
  if (ls == 0) denom[v] = ss;
}

// wave per node, lane=feature: acc = sum e_j * h[src_j]; out = acc/denom + bias
__global__ __launch_bounds__(256) void k_node_aggr(
    const int* __restrict__ rowptr, const int* __restrict__ src_sorted,
    const float* __restrict__ esort, const float* __restrict__ denom,
    const float* __restrict__ H, const float* __restrict__ bias,
    float* __restrict__ out, int n, int relu)
{
  int v = blockIdx.x * 4 + (threadIdx.x >> 6);
  int lane = threadIdx.x & 63;
  if (v >= n) return;
  int start = rowptr[v], end = rowptr[v + 1];
  float acc = 0.f;
  int j = start;
  for (; j + 1 < end; j += 2){
    int s0 = src_sorted[j], s1 = src_sorted[j + 1];
    float w0 = esort[j], w1 = esort[j + 1];
    float h0 = H[(size_t)s0 * D + lane];
    float h1 = H[(size_t)s1 * D + lane];
    acc = fmaf(h0, w0, acc);
    acc = fmaf(h1, w1, acc);
  }
  if (j < end)
    acc = fmaf(H[(size_t)src_sorted[j] * D + lane], esort[j], acc);
  float inv = 1.f / (denom[v] + 1e-16f);
  float r = acc * inv + bias[lane];
  if (relu) r = fmaxf(r, 0.f);
  out[(size_t)v * D + lane] = r;
}

extern "C" void kernel_launch(void* const* d_in, const int* in_sizes, int n_in,
                              void* d_out, int out_size, void* d_ws, size_t ws_size,
                              hipStream_t stream)
{
  const float* x    = (const float*)d_in[0];
  const int*   ei   = (const int*)d_in[1];    // integer inputs arrive as int32
  const float* ea   = (const float*)d_in[2];
  const float* W1   = (const float*)d_in[3];
  const float* We1  = (const float*)d_in[4];
  const float* as1  = (const float*)d_in[5];
  const float* ad1  = (const float*)d_in[6];
  const float* ae1  = (const float*)d_in[7];
  const float* b1   = (const float*)d_in[8];
  const float* W2   = (const float*)d_in[9];
  const float* We2  = (const float*)d_in[10];
  const float* as2  = (const float*)d_in[11];
  const float* ad2  = (const float*)d_in[12];
  const float* ae2  = (const float*)d_in[13];
  const float* b2   = (const float*)d_in[14];
  float* out = (float*)d_out;

  int n = in_sizes[0] / D;     // 100000
  int e = in_sizes[1] / 2;     // 1600000
  const int* srcp = ei;
  const int* dstp = ei + e;

  int nb = (n + 255) / 256;    // scan blocks (391)

  char* p = (char*)d_ws;
  float* buf_h   = (float*)p;  p += (size_t)n * D * 4;
  float* buf_x2  = (float*)p;  p += (size_t)n * D * 4;
  float* asrc    = (float*)p;  p += (size_t)n * 4;
  float* adst    = (float*)p;  p += (size_t)n * 4;
  float* denom   = (float*)p;  p += (size_t)n * 4;
  int*   deg     = (int*)p;    p += (size_t)n * 4;
  int*   incl    = (int*)p;    p += (size_t)n * 4;
  int*   rowptr  = (int*)p;    p += (size_t)(n + 1) * 4;
  int*   cursor  = (int*)p;    p += (size_t)n * 4;
  int*   bsum    = (int*)p;    p += (size_t)(nb + 1) * 4;
  float* ce      = (float*)p;  p += 64;  // keep 16B alignment
  int*   src_s   = (int*)p;    p += (size_t)e * 4;
  float* ea_s    = (float*)p;  p += (size_t)e * 4;
  float* esort   = (float*)p;  p += (size_t)e * 4;

  int gE  = (e + 255) / 256;
  int gR  = (n + 3) / 4;
  int gS  = (n * 16 + 255) / 256;   // softmax: 16 lanes/node
  int gA  = (n + 3) / 4;            // aggr: wave/node

  // ---- CSR build ----
  k_ce<<<1, 64, 0, stream>>>(We1, ae1, We2, ae2, ce);
  k_zero<<<nb, 256, 0, stream>>>(deg, n);
  k_hist<<<gE, 256, 0, stream>>>(dstp, deg, e);
  k_scan1<<<nb, 256, 0, stream>>>(deg, incl, bsum, n);
  k_scan2<<<1, 64, 0, stream>>>(bsum, nb);
  k_scan3<<<nb, 256, 0, stream>>>(deg, incl, bsum, rowptr, cursor, n);
  k_scatter<<<gE, 256, 0, stream>>>(srcp, dstp, ea, cursor, src_s, ea_s, e);

  // ---- layer 1 ----
  k_gemm_dots<<<gR, 256, 0, stream>>>(x, W1, as1, ad1, buf_h, asrc, adst, n);
  k_node_softmax<<<gS, 256, 0, stream>>>(rowptr, src_s, ea_s, asrc, adst, ce, 0, esort, denom, n);
  k_node_aggr<<<gA, 256, 0, stream>>>(rowptr, src_s, esort, denom, buf_h, b1, buf_x2, n, 1);

  // ---- layer 2 ----
  k_gemm_dots<<<gR, 256, 0, stream>>>(buf_x2, W2, as2, ad2, buf_h, asrc, adst, n);
  k_node_softmax<<<gS, 256, 0, stream>>>(rowptr, src_s, ea_s, asrc, adst, ce, 1, esort, denom, n);
  k_node_aggr<<<gA, 256, 0, stream>>>(rowptr, src_s, esort, denom, buf_h, b2, out, n, 0);
}